// Round 1
// baseline (406.380 us; speedup 1.0000x reference)
//
#include <hip/hip_runtime.h>

// SNN block: cur = x @ W^T + b  (f32 GEMM), then sequential leaky-integrate-fire scan.
// T=200, B=256, D_IN=512, D_H=512. BETA=0.9, THRESHOLD=1.0.
// d_out = [spk_rec (T*B*H) | mem_rec (T*B*H)] f32.
// Strategy: GEMM writes cur into the mem_rec half of d_out; scan runs in-place.

#define T_STEPS 200
#define BATCH   256
#define D_INN   512
#define D_HH    512

constexpr int MM = T_STEPS * BATCH;  // 51200
constexpr int NN = D_HH;             // 512
constexpr int KK = D_INN;            // 512

// ---------------- GEMM: C[m][n] = sum_k A[m][k]*W[n][k] + bias[n] ----------------
// BM=128, BN=128, BK=16, 256 threads, 8x8 micro-tile per thread.
__global__ __launch_bounds__(256) void gemm_nt_f32(const float* __restrict__ A,
                                                   const float* __restrict__ W,
                                                   const float* __restrict__ bias,
                                                   float* __restrict__ C) {
    __shared__ float As[16][132];  // [k][m], +4 pad
    __shared__ float Bs[16][132];  // [k][n]

    const int tid = threadIdx.x;
    const int tx = tid & 15;        // 0..15 -> col group
    const int ty = tid >> 4;        // 0..15 -> row group
    const int row0 = blockIdx.x * 128;
    const int col0 = blockIdx.y * 128;

    // staging indices: 64 rows per pass, 4 threads cover one row's 16 k's
    const int lr = tid >> 2;          // 0..63
    const int lk = (tid & 3) * 4;     // 0,4,8,12

    float acc[8][8] = {};

    for (int k0 = 0; k0 < KK; k0 += 16) {
#pragma unroll
        for (int p = 0; p < 2; ++p) {
            const int r = lr + p * 64;
            const float4 va = *reinterpret_cast<const float4*>(&A[(size_t)(row0 + r) * KK + k0 + lk]);
            As[lk + 0][r] = va.x; As[lk + 1][r] = va.y; As[lk + 2][r] = va.z; As[lk + 3][r] = va.w;
            const float4 vb = *reinterpret_cast<const float4*>(&W[(size_t)(col0 + r) * KK + k0 + lk]);
            Bs[lk + 0][r] = vb.x; Bs[lk + 1][r] = vb.y; Bs[lk + 2][r] = vb.z; Bs[lk + 3][r] = vb.w;
        }
        __syncthreads();

#pragma unroll
        for (int k = 0; k < 16; ++k) {
            float a[8], b[8];
#pragma unroll
            for (int i = 0; i < 8; ++i) a[i] = As[k][ty * 8 + i];
#pragma unroll
            for (int j = 0; j < 8; ++j) b[j] = Bs[k][tx * 8 + j];
#pragma unroll
            for (int i = 0; i < 8; ++i)
#pragma unroll
                for (int j = 0; j < 8; ++j)
                    acc[i][j] += a[i] * b[j];
        }
        __syncthreads();
    }

    // epilogue: add bias, store float4
#pragma unroll
    for (int i = 0; i < 8; ++i) {
        const int r = row0 + ty * 8 + i;
#pragma unroll
        for (int j = 0; j < 8; j += 4) {
            const int c = col0 + tx * 8 + j;
            float4 o;
            o.x = acc[i][j + 0] + bias[c + 0];
            o.y = acc[i][j + 1] + bias[c + 1];
            o.z = acc[i][j + 2] + bias[c + 2];
            o.w = acc[i][j + 3] + bias[c + 3];
            *reinterpret_cast<float4*>(&C[(size_t)r * NN + c]) = o;
        }
    }
}

// ---------------- Sequential LIF scan (in-place over cur/mem buffer) ----------------
// buf holds cur on entry; overwritten with mem_rec. spk written separately.
// reset = (mem_prev > 1); mem = 0.9*mem_prev + cur - reset; spk = (mem > 1)
__global__ __launch_bounds__(256) void snn_scan(float* buf, float* spk) {
    const int BH = BATCH * D_HH;  // 131072
    const int i = blockIdx.x * 256 + threadIdx.x;
    float mem = 0.0f;
    float c = buf[i];  // prefetch t=0
    for (int t = 0; t < T_STEPS; ++t) {
        // prefetch next timestep's current
        float cn = (t + 1 < T_STEPS) ? buf[(size_t)(t + 1) * BH + i] : 0.0f;
        const float reset = (mem > 1.0f) ? 1.0f : 0.0f;
        mem = 0.9f * mem + c - reset;
        const float s = (mem > 1.0f) ? 1.0f : 0.0f;
        spk[(size_t)t * BH + i] = s;
        buf[(size_t)t * BH + i] = mem;
        c = cn;
    }
}

extern "C" void kernel_launch(void* const* d_in, const int* in_sizes, int n_in,
                              void* d_out, int out_size, void* d_ws, size_t ws_size,
                              hipStream_t stream) {
    const float* x    = (const float*)d_in[0];  // [T,B,D_IN]
    const float* W    = (const float*)d_in[1];  // [D_H,D_IN]
    const float* bias = (const float*)d_in[2];  // [D_H]
    float* out = (float*)d_out;

    const size_t TBH = (size_t)T_STEPS * BATCH * D_HH;
    float* spk = out;        // first half
    float* mem = out + TBH;  // second half; also holds cur between the two kernels

    dim3 grid(MM / 128, NN / 128);  // 400 x 4
    gemm_nt_f32<<<grid, 256, 0, stream>>>(x, W, bias, mem);

    snn_scan<<<(BATCH * D_HH) / 256, 256, 0, stream>>>(mem, spk);
}